// Round 1
// baseline (161.858 us; speedup 1.0000x reference)
//
#include <hip/hip_runtime.h>
#include <hip/hip_bf16.h>

// ============================================================================
// ImageManifoldHead on MI355X (gfx950)
//
// Pipeline:
//   prep:  W_patch (768x512 f32) -> WpT bf16 [512][768]   (LDS tiled transpose)
//          W_out   (512x512 f32) -> WoT bf16 [512][512]
//          W_coord (512x8)  -> WcT f32 [8][512], W_spinor (512x4) -> WsT [4][512]
//   gemm1: patchify-gather + (25088x768)@(768x512) bf16 MFMA + b_patch + pos  -> x bf16
//   manifold_ln: coords/spinor/K0/embed/residual/LayerNorm, in-place on x (bf16)
//   gemm2: (25088x512)@(512x512) bf16 MFMA + b_out -> out f32
//
// ws layout (bytes):
//   [0)             x      bf16 25088*512  = 25,690,112
//   [25690112)      WpT    bf16 512*768    =    786,432
//   [26476544)      WoT    bf16 512*512    =    524,288
//   [27000832)      WcT    f32  8*512      =     16,384
//   [27017216)      WsT    f32  4*512      =      8,192
//   total ~27.0 MB
// ============================================================================

typedef __bf16 bf16_t;
typedef bf16_t bf16x8 __attribute__((ext_vector_type(8)));
typedef float  f32x4  __attribute__((ext_vector_type(4)));

#define IMG     448
#define PSZ     16
#define NHP     28
#define NPATCH  784
#define PDIM    768
#define DMODEL  512
#define MROWS   25088   // 32*784

// ---------------------------------------------------------------------------
// prep: transpose f32 [K][N] -> bf16 [N][K], 64x64 tiles, coalesced both sides
// ---------------------------------------------------------------------------
__global__ __launch_bounds__(256) void transpose_to_bf16(
    const float* __restrict__ src, bf16_t* __restrict__ dst, int K, int N)
{
  __shared__ float t[64][65];
  const int tx = threadIdx.x;      // 0..63
  const int ty = threadIdx.y;      // 0..3
  const int bx = blockIdx.x * 64;  // N offset
  const int by = blockIdx.y * 64;  // K offset
  #pragma unroll
  for (int r = ty; r < 64; r += 4)
    t[r][tx] = src[(size_t)(by + r) * N + (bx + tx)];
  __syncthreads();
  #pragma unroll
  for (int r = ty; r < 64; r += 4)
    dst[(size_t)(bx + r) * K + (by + tx)] = (bf16_t)t[tx][r];
}

// W_coord [512][8] -> WcT [8][512] f32 ; W_spinor [512][4] -> WsT [4][512] f32
__global__ __launch_bounds__(256) void small_prep(
    const float* __restrict__ Wc, const float* __restrict__ Ws,
    float* __restrict__ WcT, float* __restrict__ WsT)
{
  const int i = blockIdx.x * 256 + threadIdx.x;
  if (i < 8 * 512) {
    const int dc = i >> 9, n = i & 511;
    WcT[i] = Wc[n * 8 + dc];
  } else if (i < 12 * 512) {
    const int j = i - 8 * 512;
    const int ds = j >> 9, n = j & 511;
    WsT[j] = Ws[n * 4 + ds];
  }
}

// ---------------------------------------------------------------------------
// gemm1: x = patchify(images) @ W_patch + b_patch + pos_embed   (bf16 out)
// tile 128x128, BK=32, 4 waves (2x2), 16x16x32 bf16 MFMA
// A[m][k] = images[b, c, ph*16+i, pw*16+j], m=b*784+ph*28+pw, k=c*256+i*16+j
// ---------------------------------------------------------------------------
__global__ __launch_bounds__(256) void gemm1_patch(
    const float* __restrict__ images, const bf16_t* __restrict__ WpT,
    const float* __restrict__ b_patch, const float* __restrict__ pos_embed,
    bf16_t* __restrict__ xout)
{
  __shared__ bf16_t As[128][40];  // +8 pad: 2-way banks on b128 frag reads
  __shared__ bf16_t Bs[128][40];  // Bs holds B^T: [n_local][k_local]

  const int tid = threadIdx.x;
  const int n0 = blockIdx.x * 128;
  const int m0 = blockIdx.y * 128;

  // staging: thread -> (row sr, 16-col half sh)
  const int sr = tid >> 1;
  const int sh = tid & 1;

  const int m  = m0 + sr;
  const int b  = m / NPATCH;
  const int p  = m - b * NPATCH;
  const int ph = p / NHP;
  const int pw = p - ph * NHP;
  const float* abase = images + (size_t)(b * 3) * (IMG * IMG)
                              + (size_t)(ph * PSZ) * IMG + pw * PSZ;
  const bf16_t* brow = WpT + (size_t)(n0 + sr) * PDIM + sh * 16;

  const int wave = tid >> 6;
  const int lane = tid & 63;
  const int wm = (wave >> 1) << 6;   // 0 / 64
  const int wn = (wave & 1) << 6;    // 0 / 64
  const int lr = lane & 15;
  const int lk = (lane >> 4) << 3;   // 0,8,16,24

  f32x4 acc[4][4] = {};

  for (int ks = 0; ks < PDIM / 32; ++ks) {
    const int k0 = ks * 32;
    const int c  = k0 >> 8;           // channel
    const int ib = (k0 >> 4) & 15;    // base i within patch (even)
    const float* asrc = abase + (size_t)c * (IMG * IMG) + (ib + sh) * IMG;
    const float4 av0 = *(const float4*)(asrc + 0);
    const float4 av1 = *(const float4*)(asrc + 4);
    const float4 av2 = *(const float4*)(asrc + 8);
    const float4 av3 = *(const float4*)(asrc + 12);
    const uint4 bv0 = *(const uint4*)(brow + k0);
    const uint4 bv1 = *(const uint4*)(brow + k0 + 8);

    __syncthreads();  // previous iter's LDS reads complete

    bf16x8 a0, a1;
    a0[0] = (bf16_t)av0.x; a0[1] = (bf16_t)av0.y; a0[2] = (bf16_t)av0.z; a0[3] = (bf16_t)av0.w;
    a0[4] = (bf16_t)av1.x; a0[5] = (bf16_t)av1.y; a0[6] = (bf16_t)av1.z; a0[7] = (bf16_t)av1.w;
    a1[0] = (bf16_t)av2.x; a1[1] = (bf16_t)av2.y; a1[2] = (bf16_t)av2.z; a1[3] = (bf16_t)av2.w;
    a1[4] = (bf16_t)av3.x; a1[5] = (bf16_t)av3.y; a1[6] = (bf16_t)av3.z; a1[7] = (bf16_t)av3.w;
    *(bf16x8*)&As[sr][sh * 16]     = a0;
    *(bf16x8*)&As[sr][sh * 16 + 8] = a1;
    *(uint4*)&Bs[sr][sh * 16]      = bv0;
    *(uint4*)&Bs[sr][sh * 16 + 8]  = bv1;

    __syncthreads();  // tile staged

    bf16x8 af[4], bfr[4];
    #pragma unroll
    for (int i = 0; i < 4; ++i) af[i]  = *(const bf16x8*)&As[wm + i * 16 + lr][lk];
    #pragma unroll
    for (int j = 0; j < 4; ++j) bfr[j] = *(const bf16x8*)&Bs[wn + j * 16 + lr][lk];
    #pragma unroll
    for (int i = 0; i < 4; ++i)
      #pragma unroll
      for (int j = 0; j < 4; ++j)
        acc[i][j] = __builtin_amdgcn_mfma_f32_16x16x32_bf16(af[i], bfr[j], acc[i][j], 0, 0, 0);
  }

  // epilogue: + b_patch + pos_embed, store bf16
  // C/D layout: col = lane&15, row = (lane>>4)*4 + reg
  const int colb = n0 + wn;
  #pragma unroll
  for (int i = 0; i < 4; ++i) {
    #pragma unroll
    for (int r = 0; r < 4; ++r) {
      const int mm = m0 + wm + i * 16 + ((lane >> 4) << 2) + r;
      const int pp = mm % NPATCH;
      const float* pe = pos_embed + (size_t)pp * DMODEL;
      bf16_t* orow = xout + (size_t)mm * DMODEL;
      #pragma unroll
      for (int j = 0; j < 4; ++j) {
        const int nn = colb + j * 16 + lr;
        orow[nn] = (bf16_t)(acc[i][j][r] + b_patch[nn] + pe[nn]);
      }
    }
  }
}

// ---------------------------------------------------------------------------
// manifold_ln: per row (wave-per-row, 8 rows/wave, 32 rows/block)
//   coords = x@W_coord + b_coord ; spinor = x@W_spinor + b_spinor
//   K0 = |spinor|^2 ; x_enh = (coords@W_embed + b_embed)*K0 + x
//   x <- LN(x_enh)*gamma + beta   (in-place, bf16)
// lane owns n = 64q + lane, q=0..7 -> all LDS reads consecutive dwords
// ---------------------------------------------------------------------------
__global__ __launch_bounds__(256) void manifold_ln(
    bf16_t* __restrict__ x,
    const float* __restrict__ WcT,   // [8][512]
    const float* __restrict__ WsT,   // [4][512]
    const float* __restrict__ We,    // [8][512] (original layout)
    const float* __restrict__ b_coord, const float* __restrict__ b_spinor,
    const float* __restrict__ b_embed,
    const float* __restrict__ gamma, const float* __restrict__ beta)
{
  __shared__ float sWc[8 * 512];
  __shared__ float sWs[4 * 512];
  __shared__ float sWe[8 * 512];
  __shared__ float sbe[512], sg[512], sb[512];

  const int tid = threadIdx.x;
  for (int i = tid; i < 8 * 512; i += 256) sWc[i] = WcT[i];
  for (int i = tid; i < 4 * 512; i += 256) sWs[i] = WsT[i];
  for (int i = tid; i < 8 * 512; i += 256) sWe[i] = We[i];
  for (int i = tid; i < 512; i += 256) { sbe[i] = b_embed[i]; sg[i] = gamma[i]; sb[i] = beta[i]; }
  __syncthreads();

  const int wave = tid >> 6;
  const int lane = tid & 63;

  float bc[8], bs[4];
  #pragma unroll
  for (int dc = 0; dc < 8; ++dc) bc[dc] = b_coord[dc];
  #pragma unroll
  for (int ds = 0; ds < 4; ++ds) bs[ds] = b_spinor[ds];

  for (int rr = 0; rr < 8; ++rr) {
    const size_t mrow = (size_t)blockIdx.x * 32 + wave * 8 + rr;
    bf16_t* xrow = x + mrow * DMODEL;

    float xv[8];
    #pragma unroll
    for (int q = 0; q < 8; ++q) xv[q] = (float)xrow[q * 64 + lane];

    float ca[8] = {0, 0, 0, 0, 0, 0, 0, 0};
    float sa[4] = {0, 0, 0, 0};
    #pragma unroll
    for (int q = 0; q < 8; ++q) {
      const int n = q * 64 + lane;
      const float xq = xv[q];
      #pragma unroll
      for (int dc = 0; dc < 8; ++dc) ca[dc] += xq * sWc[dc * 512 + n];
      #pragma unroll
      for (int ds = 0; ds < 4; ++ds) sa[ds] += xq * sWs[ds * 512 + n];
    }
    #pragma unroll
    for (int off = 32; off > 0; off >>= 1) {
      #pragma unroll
      for (int dc = 0; dc < 8; ++dc) ca[dc] += __shfl_xor(ca[dc], off, 64);
      #pragma unroll
      for (int ds = 0; ds < 4; ++ds) sa[ds] += __shfl_xor(sa[ds], off, 64);
    }
    float K0 = 0.0f;
    #pragma unroll
    for (int dc = 0; dc < 8; ++dc) ca[dc] += bc[dc];
    #pragma unroll
    for (int ds = 0; ds < 4; ++ds) { sa[ds] += bs[ds]; K0 += sa[ds] * sa[ds]; }

    float xe[8], s1 = 0.0f, s2 = 0.0f;
    #pragma unroll
    for (int q = 0; q < 8; ++q) {
      const int n = q * 64 + lane;
      float xm = sbe[n];
      #pragma unroll
      for (int dc = 0; dc < 8; ++dc) xm += ca[dc] * sWe[dc * 512 + n];
      const float v = xm * K0 + xv[q];
      xe[q] = v; s1 += v; s2 += v * v;
    }
    #pragma unroll
    for (int off = 32; off > 0; off >>= 1) {
      s1 += __shfl_xor(s1, off, 64);
      s2 += __shfl_xor(s2, off, 64);
    }
    const float mu  = s1 * (1.0f / 512.0f);
    const float var = s2 * (1.0f / 512.0f) - mu * mu;
    const float rs  = rsqrtf(var + 1e-5f);
    #pragma unroll
    for (int q = 0; q < 8; ++q) {
      const int n = q * 64 + lane;
      xrow[n] = (bf16_t)((xe[q] - mu) * rs * sg[n] + sb[n]);
    }
  }
}

// ---------------------------------------------------------------------------
// gemm2: out = x_norm @ W_out + b_out   (f32 out)
// ---------------------------------------------------------------------------
__global__ __launch_bounds__(256) void gemm2_out(
    const bf16_t* __restrict__ xn, const bf16_t* __restrict__ WoT,
    const float* __restrict__ b_out, float* __restrict__ out)
{
  __shared__ bf16_t As[128][40];
  __shared__ bf16_t Bs[128][40];

  const int tid = threadIdx.x;
  const int n0 = blockIdx.x * 128;
  const int m0 = blockIdx.y * 128;
  const int sr = tid >> 1;
  const int sh = tid & 1;

  const bf16_t* arow = xn  + (size_t)(m0 + sr) * DMODEL + sh * 16;
  const bf16_t* brow = WoT + (size_t)(n0 + sr) * DMODEL + sh * 16;

  const int wave = tid >> 6;
  const int lane = tid & 63;
  const int wm = (wave >> 1) << 6;
  const int wn = (wave & 1) << 6;
  const int lr = lane & 15;
  const int lk = (lane >> 4) << 3;

  f32x4 acc[4][4] = {};

  for (int ks = 0; ks < DMODEL / 32; ++ks) {
    const int k0 = ks * 32;
    const uint4 a0 = *(const uint4*)(arow + k0);
    const uint4 a1 = *(const uint4*)(arow + k0 + 8);
    const uint4 b0 = *(const uint4*)(brow + k0);
    const uint4 b1 = *(const uint4*)(brow + k0 + 8);

    __syncthreads();
    *(uint4*)&As[sr][sh * 16]     = a0;
    *(uint4*)&As[sr][sh * 16 + 8] = a1;
    *(uint4*)&Bs[sr][sh * 16]     = b0;
    *(uint4*)&Bs[sr][sh * 16 + 8] = b1;
    __syncthreads();

    bf16x8 af[4], bfr[4];
    #pragma unroll
    for (int i = 0; i < 4; ++i) af[i]  = *(const bf16x8*)&As[wm + i * 16 + lr][lk];
    #pragma unroll
    for (int j = 0; j < 4; ++j) bfr[j] = *(const bf16x8*)&Bs[wn + j * 16 + lr][lk];
    #pragma unroll
    for (int i = 0; i < 4; ++i)
      #pragma unroll
      for (int j = 0; j < 4; ++j)
        acc[i][j] = __builtin_amdgcn_mfma_f32_16x16x32_bf16(af[i], bfr[j], acc[i][j], 0, 0, 0);
  }

  const int colb = n0 + wn;
  #pragma unroll
  for (int i = 0; i < 4; ++i) {
    #pragma unroll
    for (int r = 0; r < 4; ++r) {
      const int mm = m0 + wm + i * 16 + ((lane >> 4) << 2) + r;
      float* orow = out + (size_t)mm * DMODEL;
      #pragma unroll
      for (int j = 0; j < 4; ++j) {
        const int nn = colb + j * 16 + lr;
        orow[nn] = acc[i][j][r] + b_out[nn];
      }
    }
  }
}

// ---------------------------------------------------------------------------
extern "C" void kernel_launch(void* const* d_in, const int* in_sizes, int n_in,
                              void* d_out, int out_size, void* d_ws, size_t ws_size,
                              hipStream_t stream)
{
  const float* images    = (const float*)d_in[0];
  const float* W_patch   = (const float*)d_in[1];
  const float* b_patch   = (const float*)d_in[2];
  const float* pos_embed = (const float*)d_in[3];
  const float* W_coord   = (const float*)d_in[4];
  const float* b_coord   = (const float*)d_in[5];
  const float* W_spinor  = (const float*)d_in[6];
  const float* b_spinor  = (const float*)d_in[7];
  const float* W_embed   = (const float*)d_in[8];
  const float* b_embed   = (const float*)d_in[9];
  const float* ln_gamma  = (const float*)d_in[10];
  const float* ln_beta   = (const float*)d_in[11];
  const float* W_out     = (const float*)d_in[12];
  const float* b_out     = (const float*)d_in[13];
  float* out = (float*)d_out;

  char* ws = (char*)d_ws;
  bf16_t* x   = (bf16_t*)(ws);
  bf16_t* WpT = (bf16_t*)(ws + 25690112);
  bf16_t* WoT = (bf16_t*)(ws + 25690112 + 786432);
  float*  WcT = (float*) (ws + 25690112 + 786432 + 524288);
  float*  WsT = (float*) (ws + 25690112 + 786432 + 524288 + 16384);

  hipLaunchKernelGGL(transpose_to_bf16, dim3(8, 12), dim3(64, 4), 0, stream,
                     W_patch, WpT, PDIM, DMODEL);
  hipLaunchKernelGGL(transpose_to_bf16, dim3(8, 8), dim3(64, 4), 0, stream,
                     W_out, WoT, DMODEL, DMODEL);
  hipLaunchKernelGGL(small_prep, dim3(24), dim3(256), 0, stream,
                     W_coord, W_spinor, WcT, WsT);
  hipLaunchKernelGGL(gemm1_patch, dim3(4, 196), dim3(256), 0, stream,
                     images, WpT, b_patch, pos_embed, x);
  hipLaunchKernelGGL(manifold_ln, dim3(784), dim3(256), 0, stream,
                     x, WcT, WsT, W_embed, b_coord, b_spinor, b_embed, ln_gamma, ln_beta);
  hipLaunchKernelGGL(gemm2_out, dim3(4, 196), dim3(256), 0, stream,
                     x, WoT, b_out, out);
}

// Round 2
// 150.290 us; speedup vs baseline: 1.0770x; 1.0770x over previous
//
#include <hip/hip_runtime.h>
#include <hip/hip_bf16.h>
#include <stdint.h>

// ============================================================================
// ImageManifoldHead on MI355X (gfx950) — round 2
//
// Pipeline (main path, needs ~65.6 MB ws):
//   prep:   W_patch -> WpT bf16 [512][768]; W_out -> WoT bf16 [512][512]
//           W_coord -> WcT f32 [8][512];    W_spinor -> WsT f32 [4][512]
//   patchify_bf16: images f32 -> Apat bf16 [25088][768]  (unfold layout)
//   gemm1:  Apat @ WpT^T + b_patch + pos  -> x bf16      (m97 structure)
//   manifold_ln: coords/spinor/K0/embed/residual/LN in-place on x
//   gemm2:  x @ WoT^T + b_out -> out f32                 (m97 structure)
//
// Both GEMMs: 128x128 tile, BK=32, 4 waves (2x2), 16x16x32 bf16 MFMA,
// global_load_lds width=16 for A and B, linear LDS, XCD-bijective swizzle.
// ============================================================================

typedef __bf16 bf16_t;
typedef bf16_t bf16x8 __attribute__((ext_vector_type(8)));
typedef bf16_t bf16x4 __attribute__((ext_vector_type(4)));
typedef float  f32x4  __attribute__((ext_vector_type(4)));

#define IMG     448
#define PSZ     16
#define NHP     28
#define NPATCH  784
#define PDIM    768
#define DMODEL  512
#define MROWS   25088

// async global->LDS, 16B per lane; lds must be wave-uniform base (HW adds lane*16)
__device__ __forceinline__ void gload16(void* lds, const void* g) {
  __builtin_amdgcn_global_load_lds(
      (__attribute__((address_space(1))) void*)(uintptr_t)g,
      (__attribute__((address_space(3))) void*)lds,
      16, 0, 0);
}

// ---------------------------------------------------------------------------
// prep: transpose f32 [K][N] -> bf16 [N][K]
// ---------------------------------------------------------------------------
__global__ __launch_bounds__(256) void transpose_to_bf16(
    const float* __restrict__ src, bf16_t* __restrict__ dst, int K, int N)
{
  __shared__ float t[64][65];
  const int tx = threadIdx.x;
  const int ty = threadIdx.y;
  const int bx = blockIdx.x * 64;
  const int by = blockIdx.y * 64;
  #pragma unroll
  for (int r = ty; r < 64; r += 4)
    t[r][tx] = src[(size_t)(by + r) * N + (bx + tx)];
  __syncthreads();
  #pragma unroll
  for (int r = ty; r < 64; r += 4)
    dst[(size_t)(bx + r) * K + (by + tx)] = (bf16_t)t[tx][r];
}

__global__ __launch_bounds__(256) void small_prep(
    const float* __restrict__ Wc, const float* __restrict__ Ws,
    float* __restrict__ WcT, float* __restrict__ WsT)
{
  const int i = blockIdx.x * 256 + threadIdx.x;
  if (i < 8 * 512) {
    const int dc = i >> 9, n = i & 511;
    WcT[i] = Wc[n * 8 + dc];
  } else if (i < 12 * 512) {
    const int j = i - 8 * 512;
    const int ds = j >> 9, n = j & 511;
    WsT[j] = Ws[n * 4 + ds];
  }
}

// ---------------------------------------------------------------------------
// patchify_bf16: images (B,3,448,448) f32 -> Apat [25088][768] bf16
// Apat[b*784+ph*28+pw][c*256+i*16+j] = images[b,c,ph*16+i,pw*16+j]
// one block per (b,c,ph): stage 16x448 strip in LDS, write 28 patch chunks
// ---------------------------------------------------------------------------
__global__ __launch_bounds__(256) void patchify_bf16(
    const float* __restrict__ images, bf16_t* __restrict__ Apat)
{
  __shared__ bf16_t t[16][456];  // pad 448->456: breaks 16-way bank conflict
  const int tid = threadIdx.x;
  const int bid = blockIdx.x;
  const int b = bid / 84, rem = bid % 84;
  const int c = rem / 28, ph = rem % 28;
  const float* src = images + ((size_t)(b * 3 + c) * IMG + ph * PSZ) * IMG;

  #pragma unroll
  for (int idx = tid; idx < 16 * 112; idx += 256) {
    const int i = idx / 112, x4 = idx % 112;
    const float4 v = *(const float4*)(src + (size_t)i * IMG + x4 * 4);
    bf16x4 w;
    w[0] = (bf16_t)v.x; w[1] = (bf16_t)v.y; w[2] = (bf16_t)v.z; w[3] = (bf16_t)v.w;
    *(bf16x4*)&t[i][x4 * 4] = w;
  }
  __syncthreads();

  const size_t mbase = (size_t)b * NPATCH + (size_t)ph * NHP;
  #pragma unroll
  for (int idx = tid; idx < 28 * 64; idx += 256) {
    const int pw = idx >> 6, e = idx & 63;
    const int i = e >> 2, j4 = e & 3;
    const bf16x4 w = *(const bf16x4*)&t[i][pw * 16 + j4 * 4];
    *(bf16x4*)&Apat[(mbase + pw) * PDIM + c * 256 + i * 16 + j4 * 4] = w;
  }
}

// ---------------------------------------------------------------------------
// gemm (m97 structure): C[M][512] = A[M][KDIM] @ BT[512][KDIM]^T
// EPI 0: out bf16, + bias + pos_embed[m%784]   EPI 1: out f32, + bias
// grid = 784 (1D), XCD-bijective swizzle (784 = 8*98)
// ---------------------------------------------------------------------------
template<int KDIM, int EPI>
__global__ __launch_bounds__(256) void gemm_bf16(
    const bf16_t* __restrict__ A, const bf16_t* __restrict__ BT,
    const float* __restrict__ bias, const float* __restrict__ pos,
    void* __restrict__ outp)
{
  __shared__ bf16_t As[128][32];
  __shared__ bf16_t Bs[128][32];

  const int tid  = threadIdx.x;
  const int orig = blockIdx.x;
  const int wg   = (orig & 7) * 98 + (orig >> 3);   // XCD chunking, bijective
  const int n0   = (wg & 3) * 128;
  const int m0   = (wg >> 2) * 128;

  const int wave = tid >> 6, lane = tid & 63;
  const int rsub = lane >> 2;        // 0..15 row within 16-row group
  const int cb   = (lane & 3) * 8;   // k element offset

  const bf16_t* agp0 = A  + ((size_t)(m0 + 32 * wave) + rsub)      * KDIM + cb;
  const bf16_t* agp1 = A  + ((size_t)(m0 + 32 * wave) + 16 + rsub) * KDIM + cb;
  const bf16_t* bgp0 = BT + ((size_t)(n0 + 32 * wave) + rsub)      * KDIM + cb;
  const bf16_t* bgp1 = BT + ((size_t)(n0 + 32 * wave) + 16 + rsub) * KDIM + cb;
  bf16_t* alds0 = &As[32 * wave][0];
  bf16_t* alds1 = &As[32 * wave + 16][0];
  bf16_t* blds0 = &Bs[32 * wave][0];
  bf16_t* blds1 = &Bs[32 * wave + 16][0];

  const int wm = (wave >> 1) << 6;
  const int wn = (wave & 1) << 6;
  const int lr = lane & 15;
  const int lk = (lane >> 4) << 3;

  f32x4 acc[4][4] = {};

  for (int k0 = 0; k0 < KDIM; k0 += 32) {
    __syncthreads();                 // prev iter's LDS reads complete
    gload16(alds0, agp0 + k0);
    gload16(alds1, agp1 + k0);
    gload16(blds0, bgp0 + k0);
    gload16(blds1, bgp1 + k0);
    __syncthreads();                 // implies vmcnt(0): DMA landed

    bf16x8 af[4], bfr[4];
    #pragma unroll
    for (int i = 0; i < 4; ++i) af[i]  = *(const bf16x8*)&As[wm + i * 16 + lr][lk];
    #pragma unroll
    for (int j = 0; j < 4; ++j) bfr[j] = *(const bf16x8*)&Bs[wn + j * 16 + lr][lk];
    #pragma unroll
    for (int i = 0; i < 4; ++i)
      #pragma unroll
      for (int j = 0; j < 4; ++j)
        acc[i][j] = __builtin_amdgcn_mfma_f32_16x16x32_bf16(af[i], bfr[j], acc[i][j], 0, 0, 0);
  }

  // C/D layout: col = lane&15 (n), row = (lane>>4)*4 + reg (m)
  const int q4 = (lane >> 4) << 2;
  const int colb = n0 + wn;
  #pragma unroll
  for (int i = 0; i < 4; ++i) {
    #pragma unroll
    for (int r = 0; r < 4; ++r) {
      const int mm = m0 + wm + i * 16 + q4 + r;
      if (EPI == 0) {
        const int pp = mm % NPATCH;
        const float* pe = pos + (size_t)pp * DMODEL;
        bf16_t* orow = (bf16_t*)outp + (size_t)mm * DMODEL;
        #pragma unroll
        for (int j = 0; j < 4; ++j) {
          const int nn = colb + j * 16 + lr;
          orow[nn] = (bf16_t)(acc[i][j][r] + bias[nn] + pe[nn]);
        }
      } else {
        float* orow = (float*)outp + (size_t)mm * DMODEL;
        #pragma unroll
        for (int j = 0; j < 4; ++j) {
          const int nn = colb + j * 16 + lr;
          orow[nn] = acc[i][j][r] + bias[nn];
        }
      }
    }
  }
}

// ---------------------------------------------------------------------------
// fallback gemm1 (round-1 fused patchify) — used only if ws too small
// ---------------------------------------------------------------------------
__global__ __launch_bounds__(256) void gemm1_fused_fallback(
    const float* __restrict__ images, const bf16_t* __restrict__ WpT,
    const float* __restrict__ b_patch, const float* __restrict__ pos_embed,
    bf16_t* __restrict__ xout)
{
  __shared__ bf16_t As[128][40];
  __shared__ bf16_t Bs[128][40];
  const int tid = threadIdx.x;
  const int n0 = blockIdx.x * 128;
  const int m0 = blockIdx.y * 128;
  const int sr = tid >> 1;
  const int sh = tid & 1;
  const int m  = m0 + sr;
  const int b  = m / NPATCH;
  const int p  = m - b * NPATCH;
  const int ph = p / NHP;
  const int pw = p - ph * NHP;
  const float* abase = images + (size_t)(b * 3) * (IMG * IMG)
                              + (size_t)(ph * PSZ) * IMG + pw * PSZ;
  const bf16_t* brow = WpT + (size_t)(n0 + sr) * PDIM + sh * 16;
  const int wave = tid >> 6;
  const int lane = tid & 63;
  const int wm = (wave >> 1) << 6;
  const int wn = (wave & 1) << 6;
  const int lr = lane & 15;
  const int lk = (lane >> 4) << 3;
  f32x4 acc[4][4] = {};
  for (int ks = 0; ks < PDIM / 32; ++ks) {
    const int k0 = ks * 32;
    const int c  = k0 >> 8;
    const int ib = (k0 >> 4) & 15;
    const float* asrc = abase + (size_t)c * (IMG * IMG) + (ib + sh) * IMG;
    const float4 av0 = *(const float4*)(asrc + 0);
    const float4 av1 = *(const float4*)(asrc + 4);
    const float4 av2 = *(const float4*)(asrc + 8);
    const float4 av3 = *(const float4*)(asrc + 12);
    const uint4 bv0 = *(const uint4*)(brow + k0);
    const uint4 bv1 = *(const uint4*)(brow + k0 + 8);
    __syncthreads();
    bf16x8 a0, a1;
    a0[0] = (bf16_t)av0.x; a0[1] = (bf16_t)av0.y; a0[2] = (bf16_t)av0.z; a0[3] = (bf16_t)av0.w;
    a0[4] = (bf16_t)av1.x; a0[5] = (bf16_t)av1.y; a0[6] = (bf16_t)av1.z; a0[7] = (bf16_t)av1.w;
    a1[0] = (bf16_t)av2.x; a1[1] = (bf16_t)av2.y; a1[2] = (bf16_t)av2.z; a1[3] = (bf16_t)av2.w;
    a1[4] = (bf16_t)av3.x; a1[5] = (bf16_t)av3.y; a1[6] = (bf16_t)av3.z; a1[7] = (bf16_t)av3.w;
    *(bf16x8*)&As[sr][sh * 16]     = a0;
    *(bf16x8*)&As[sr][sh * 16 + 8] = a1;
    *(uint4*)&Bs[sr][sh * 16]      = bv0;
    *(uint4*)&Bs[sr][sh * 16 + 8]  = bv1;
    __syncthreads();
    bf16x8 af[4], bfr[4];
    #pragma unroll
    for (int i = 0; i < 4; ++i) af[i]  = *(const bf16x8*)&As[wm + i * 16 + lr][lk];
    #pragma unroll
    for (int j = 0; j < 4; ++j) bfr[j] = *(const bf16x8*)&Bs[wn + j * 16 + lr][lk];
    #pragma unroll
    for (int i = 0; i < 4; ++i)
      #pragma unroll
      for (int j = 0; j < 4; ++j)
        acc[i][j] = __builtin_amdgcn_mfma_f32_16x16x32_bf16(af[i], bfr[j], acc[i][j], 0, 0, 0);
  }
  const int colb = n0 + wn;
  #pragma unroll
  for (int i = 0; i < 4; ++i) {
    #pragma unroll
    for (int r = 0; r < 4; ++r) {
      const int mm = m0 + wm + i * 16 + ((lane >> 4) << 2) + r;
      const int pp = mm % NPATCH;
      const float* pe = pos_embed + (size_t)pp * DMODEL;
      bf16_t* orow = xout + (size_t)mm * DMODEL;
      #pragma unroll
      for (int j = 0; j < 4; ++j) {
        const int nn = colb + j * 16 + lr;
        orow[nn] = (bf16_t)(acc[i][j][r] + b_patch[nn] + pe[nn]);
      }
    }
  }
}

// ---------------------------------------------------------------------------
// manifold_ln: in-place on x (bf16), wave-per-row
// ---------------------------------------------------------------------------
__global__ __launch_bounds__(256) void manifold_ln(
    bf16_t* __restrict__ x,
    const float* __restrict__ WcT,
    const float* __restrict__ WsT,
    const float* __restrict__ We,
    const float* __restrict__ b_coord, const float* __restrict__ b_spinor,
    const float* __restrict__ b_embed,
    const float* __restrict__ gamma, const float* __restrict__ beta)
{
  __shared__ float sWc[8 * 512];
  __shared__ float sWs[4 * 512];
  __shared__ float sWe[8 * 512];
  __shared__ float sbe[512], sg[512], sb[512];

  const int tid = threadIdx.x;
  for (int i = tid; i < 8 * 512; i += 256) sWc[i] = WcT[i];
  for (int i = tid; i < 4 * 512; i += 256) sWs[i] = WsT[i];
  for (int i = tid; i < 8 * 512; i += 256) sWe[i] = We[i];
  for (int i = tid; i < 512; i += 256) { sbe[i] = b_embed[i]; sg[i] = gamma[i]; sb[i] = beta[i]; }
  __syncthreads();

  const int wave = tid >> 6;
  const int lane = tid & 63;

  float bc[8], bs[4];
  #pragma unroll
  for (int dc = 0; dc < 8; ++dc) bc[dc] = b_coord[dc];
  #pragma unroll
  for (int ds = 0; ds < 4; ++ds) bs[ds] = b_spinor[ds];

  for (int rr = 0; rr < 8; ++rr) {
    const size_t mrow = (size_t)blockIdx.x * 32 + wave * 8 + rr;
    bf16_t* xrow = x + mrow * DMODEL;

    float xv[8];
    #pragma unroll
    for (int q = 0; q < 8; ++q) xv[q] = (float)xrow[q * 64 + lane];

    float ca[8] = {0, 0, 0, 0, 0, 0, 0, 0};
    float sa[4] = {0, 0, 0, 0};
    #pragma unroll
    for (int q = 0; q < 8; ++q) {
      const int n = q * 64 + lane;
      const float xq = xv[q];
      #pragma unroll
      for (int dc = 0; dc < 8; ++dc) ca[dc] += xq * sWc[dc * 512 + n];
      #pragma unroll
      for (int ds = 0; ds < 4; ++ds) sa[ds] += xq * sWs[ds * 512 + n];
    }
    #pragma unroll
    for (int off = 32; off > 0; off >>= 1) {
      #pragma unroll
      for (int dc = 0; dc < 8; ++dc) ca[dc] += __shfl_xor(ca[dc], off, 64);
      #pragma unroll
      for (int ds = 0; ds < 4; ++ds) sa[ds] += __shfl_xor(sa[ds], off, 64);
    }
    float K0 = 0.0f;
    #pragma unroll
    for (int dc = 0; dc < 8; ++dc) ca[dc] += bc[dc];
    #pragma unroll
    for (int ds = 0; ds < 4; ++ds) { sa[ds] += bs[ds]; K0 += sa[ds] * sa[ds]; }

    float xe[8], s1 = 0.0f, s2 = 0.0f;
    #pragma unroll
    for (int q = 0; q < 8; ++q) {
      const int n = q * 64 + lane;
      float xm = sbe[n];
      #pragma unroll
      for (int dc = 0; dc < 8; ++dc) xm += ca[dc] * sWe[dc * 512 + n];
      const float v = xm * K0 + xv[q];
      xe[q] = v; s1 += v; s2 += v * v;
    }
    #pragma unroll
    for (int off = 32; off > 0; off >>= 1) {
      s1 += __shfl_xor(s1, off, 64);
      s2 += __shfl_xor(s2, off, 64);
    }
    const float mu  = s1 * (1.0f / 512.0f);
    const float var = s2 * (1.0f / 512.0f) - mu * mu;
    const float rs  = rsqrtf(var + 1e-5f);
    #pragma unroll
    for (int q = 0; q < 8; ++q) {
      const int n = q * 64 + lane;
      xrow[n] = (bf16_t)((xe[q] - mu) * rs * sg[n] + sb[n]);
    }
  }
}

// ---------------------------------------------------------------------------
extern "C" void kernel_launch(void* const* d_in, const int* in_sizes, int n_in,
                              void* d_out, int out_size, void* d_ws, size_t ws_size,
                              hipStream_t stream)
{
  const float* images    = (const float*)d_in[0];
  const float* W_patch   = (const float*)d_in[1];
  const float* b_patch   = (const float*)d_in[2];
  const float* pos_embed = (const float*)d_in[3];
  const float* W_coord   = (const float*)d_in[4];
  const float* b_coord   = (const float*)d_in[5];
  const float* W_spinor  = (const float*)d_in[6];
  const float* b_spinor  = (const float*)d_in[7];
  const float* W_embed   = (const float*)d_in[8];
  const float* b_embed   = (const float*)d_in[9];
  const float* ln_gamma  = (const float*)d_in[10];
  const float* ln_beta   = (const float*)d_in[11];
  const float* W_out     = (const float*)d_in[12];
  const float* b_out     = (const float*)d_in[13];
  float* out = (float*)d_out;

  const size_t SZ_APAT = (size_t)MROWS * PDIM * 2;     // 38,535,168
  const size_t SZ_X    = (size_t)MROWS * DMODEL * 2;   // 25,690,112
  const size_t SZ_WPT  = (size_t)DMODEL * PDIM * 2;    //    786,432
  const size_t SZ_WOT  = (size_t)DMODEL * DMODEL * 2;  //    524,288
  const size_t NEED_FULL = SZ_APAT + SZ_X + SZ_WPT + SZ_WOT + 16384 + 8192;

  char* ws = (char*)d_ws;
  const bool full = (ws_size >= NEED_FULL);

  bf16_t* Apat; bf16_t* x; bf16_t* WpT; bf16_t* WoT; float* WcT; float* WsT;
  if (full) {
    Apat = (bf16_t*)(ws);
    x    = (bf16_t*)(ws + SZ_APAT);
    WpT  = (bf16_t*)(ws + SZ_APAT + SZ_X);
    WoT  = (bf16_t*)(ws + SZ_APAT + SZ_X + SZ_WPT);
    WcT  = (float*) (ws + SZ_APAT + SZ_X + SZ_WPT + SZ_WOT);
    WsT  = (float*) (ws + SZ_APAT + SZ_X + SZ_WPT + SZ_WOT + 16384);
  } else {
    Apat = nullptr;
    x    = (bf16_t*)(ws);
    WpT  = (bf16_t*)(ws + SZ_X);
    WoT  = (bf16_t*)(ws + SZ_X + SZ_WPT);
    WcT  = (float*) (ws + SZ_X + SZ_WPT + SZ_WOT);
    WsT  = (float*) (ws + SZ_X + SZ_WPT + SZ_WOT + 16384);
  }

  hipLaunchKernelGGL(transpose_to_bf16, dim3(8, 12), dim3(64, 4), 0, stream,
                     W_patch, WpT, PDIM, DMODEL);
  hipLaunchKernelGGL(transpose_to_bf16, dim3(8, 8), dim3(64, 4), 0, stream,
                     W_out, WoT, DMODEL, DMODEL);
  hipLaunchKernelGGL(small_prep, dim3(24), dim3(256), 0, stream,
                     W_coord, W_spinor, WcT, WsT);

  if (full) {
    hipLaunchKernelGGL(patchify_bf16, dim3(32 * 3 * 28), dim3(256), 0, stream,
                       images, Apat);
    hipLaunchKernelGGL((gemm_bf16<PDIM, 0>), dim3(784), dim3(256), 0, stream,
                       Apat, WpT, b_patch, pos_embed, (void*)x);
  } else {
    hipLaunchKernelGGL(gemm1_fused_fallback, dim3(4, 196), dim3(256), 0, stream,
                       images, WpT, b_patch, pos_embed, x);
  }

  hipLaunchKernelGGL(manifold_ln, dim3(784), dim3(256), 0, stream,
                     x, WcT, WsT, W_embed, b_coord, b_spinor, b_embed, ln_gamma, ln_beta);

  hipLaunchKernelGGL((gemm_bf16<DMODEL, 1>), dim3(784), dim3(256), 0, stream,
                     x, WoT, b_out, (const float*)nullptr, (void*)out);
}

// Round 3
// 126.103 us; speedup vs baseline: 1.2835x; 1.1918x over previous
//
#include <hip/hip_runtime.h>
#include <hip/hip_bf16.h>
#include <stdint.h>

// ============================================================================
// ImageManifoldHead on MI355X (gfx950) — round 3
//
// Pipeline (main path):
//   prep:   W_patch -> WpT bf16 [512][768]; W_out -> WoT bf16 [512][512]
//           manifold_prep: Wcsg bf16[16][512] (Wc | Ws_hi | Ws_lo),
//                          Wcs2g bf16[8][512] (Wc_lo),
//                          Wetg bf16[512][24] (We dup x2 | be_hi | be_lo | 0)
//   patchify_bf16: images f32 -> Apat bf16 [25088][768]
//   gemm1:  Apat @ WpT^T + b_patch + pos  -> x bf16      (m97 structure)
//   manifold_ln_v3: MFMA-based coords/spinor/K0/embed/residual/LN, in-place
//   gemm2:  x @ WoT^T + b_out -> out f32                 (m97 structure)
// ============================================================================

typedef __bf16 bf16_t;
typedef bf16_t bf16x8 __attribute__((ext_vector_type(8)));
typedef bf16_t bf16x4 __attribute__((ext_vector_type(4)));
typedef float  f32x4  __attribute__((ext_vector_type(4)));

#define IMG     448
#define PSZ     16
#define NHP     28
#define NPATCH  784
#define PDIM    768
#define DMODEL  512
#define MROWS   25088

__device__ __forceinline__ void gload16(void* lds, const void* g) {
  __builtin_amdgcn_global_load_lds(
      (__attribute__((address_space(1))) void*)(uintptr_t)g,
      (__attribute__((address_space(3))) void*)lds,
      16, 0, 0);
}

__device__ __forceinline__ unsigned short bfbits(float v) {
  bf16_t h = (bf16_t)v;
  unsigned short u;
  __builtin_memcpy(&u, &h, 2);
  return u;
}
__device__ __forceinline__ float f_from_bits(unsigned u) {
  float f; __builtin_memcpy(&f, &u, 4); return f;
}

// ---------------------------------------------------------------------------
// prep: transpose f32 [K][N] -> bf16 [N][K]
// ---------------------------------------------------------------------------
__global__ __launch_bounds__(256) void transpose_to_bf16(
    const float* __restrict__ src, bf16_t* __restrict__ dst, int K, int N)
{
  __shared__ float t[64][65];
  const int tx = threadIdx.x;
  const int ty = threadIdx.y;
  const int bx = blockIdx.x * 64;
  const int by = blockIdx.y * 64;
  #pragma unroll
  for (int r = ty; r < 64; r += 4)
    t[r][tx] = src[(size_t)(by + r) * N + (bx + tx)];
  __syncthreads();
  #pragma unroll
  for (int r = ty; r < 64; r += 4)
    dst[(size_t)(bx + r) * K + (by + tx)] = (bf16_t)t[tx][r];
}

// ---------------------------------------------------------------------------
// manifold_prep: pack manifold weights for the MFMA kernel
//  Wcsg  [16][512]: r<8: bf16(W_coord[n][r]); 8..11: hi(W_spinor[n][r-8]);
//                   12..15: lo(W_spinor[n][r-12])
//  Wcs2g [8][512] : lo(W_coord[n][r])
//  Wetg  [512][24]: k<16: bf16(W_embed[k&7][n]); k16: hi(be[n]); k17: lo(be[n]); else 0
// ---------------------------------------------------------------------------
__global__ __launch_bounds__(256) void manifold_prep(
    const float* __restrict__ Wc, const float* __restrict__ Ws,
    const float* __restrict__ We, const float* __restrict__ be,
    bf16_t* __restrict__ Wcsg, bf16_t* __restrict__ Wcs2g, bf16_t* __restrict__ Wetg)
{
  const int idx = blockIdx.x * 256 + threadIdx.x;   // grid 96 -> 24576
  if (idx < 8192) {
    const int r = idx >> 9, n = idx & 511;
    float v;
    if (r < 8)       v = Wc[n * 8 + r];
    else if (r < 12) v = Ws[n * 4 + (r - 8)];
    else { const float f = Ws[n * 4 + (r - 12)]; v = f - (float)(bf16_t)f; }
    Wcsg[idx] = (bf16_t)v;
  } else if (idx < 12288) {
    const int j = idx - 8192;
    const int r = j >> 9, n = j & 511;
    const float f = Wc[n * 8 + r];
    Wcs2g[j] = (bf16_t)(f - (float)(bf16_t)f);
  } else if (idx < 24576) {
    const int j = idx - 12288;
    const int n = j / 24, k = j % 24;
    float v = 0.f;
    if (k < 16)      v = We[(k & 7) * 512 + n];
    else if (k == 16) v = be[n];
    else if (k == 17) { const float f = be[n]; v = f - (float)(bf16_t)f; }
    Wetg[j] = (bf16_t)v;
  }
}

// ---------------------------------------------------------------------------
// patchify_bf16: images (B,3,448,448) f32 -> Apat [25088][768] bf16
// ---------------------------------------------------------------------------
__global__ __launch_bounds__(256) void patchify_bf16(
    const float* __restrict__ images, bf16_t* __restrict__ Apat)
{
  __shared__ bf16_t t[16][456];
  const int tid = threadIdx.x;
  const int bid = blockIdx.x;
  const int b = bid / 84, rem = bid % 84;
  const int c = rem / 28, ph = rem % 28;
  const float* src = images + ((size_t)(b * 3 + c) * IMG + ph * PSZ) * IMG;

  #pragma unroll
  for (int idx = tid; idx < 16 * 112; idx += 256) {
    const int i = idx / 112, x4 = idx % 112;
    const float4 v = *(const float4*)(src + (size_t)i * IMG + x4 * 4);
    bf16x4 w;
    w[0] = (bf16_t)v.x; w[1] = (bf16_t)v.y; w[2] = (bf16_t)v.z; w[3] = (bf16_t)v.w;
    *(bf16x4*)&t[i][x4 * 4] = w;
  }
  __syncthreads();

  const size_t mbase = (size_t)b * NPATCH + (size_t)ph * NHP;
  #pragma unroll
  for (int idx = tid; idx < 28 * 64; idx += 256) {
    const int pw = idx >> 6, e = idx & 63;
    const int i = e >> 2, j4 = e & 3;
    const bf16x4 w = *(const bf16x4*)&t[i][pw * 16 + j4 * 4];
    *(bf16x4*)&Apat[(mbase + pw) * PDIM + c * 256 + i * 16 + j4 * 4] = w;
  }
}

// ---------------------------------------------------------------------------
// gemm (m97 structure): C[M][512] = A[M][KDIM] @ BT[512][KDIM]^T
// ---------------------------------------------------------------------------
template<int KDIM, int EPI>
__global__ __launch_bounds__(256) void gemm_bf16(
    const bf16_t* __restrict__ A, const bf16_t* __restrict__ BT,
    const float* __restrict__ bias, const float* __restrict__ pos,
    void* __restrict__ outp)
{
  __shared__ bf16_t As[128][32];
  __shared__ bf16_t Bs[128][32];

  const int tid  = threadIdx.x;
  const int orig = blockIdx.x;
  const int wg   = (orig & 7) * 98 + (orig >> 3);
  const int n0   = (wg & 3) * 128;
  const int m0   = (wg >> 2) * 128;

  const int wave = tid >> 6, lane = tid & 63;
  const int rsub = lane >> 2;
  const int cb   = (lane & 3) * 8;

  const bf16_t* agp0 = A  + ((size_t)(m0 + 32 * wave) + rsub)      * KDIM + cb;
  const bf16_t* agp1 = A  + ((size_t)(m0 + 32 * wave) + 16 + rsub) * KDIM + cb;
  const bf16_t* bgp0 = BT + ((size_t)(n0 + 32 * wave) + rsub)      * KDIM + cb;
  const bf16_t* bgp1 = BT + ((size_t)(n0 + 32 * wave) + 16 + rsub) * KDIM + cb;
  bf16_t* alds0 = &As[32 * wave][0];
  bf16_t* alds1 = &As[32 * wave + 16][0];
  bf16_t* blds0 = &Bs[32 * wave][0];
  bf16_t* blds1 = &Bs[32 * wave + 16][0];

  const int wm = (wave >> 1) << 6;
  const int wn = (wave & 1) << 6;
  const int lr = lane & 15;
  const int lk = (lane >> 4) << 3;

  f32x4 acc[4][4] = {};

  for (int k0 = 0; k0 < KDIM; k0 += 32) {
    __syncthreads();
    gload16(alds0, agp0 + k0);
    gload16(alds1, agp1 + k0);
    gload16(blds0, bgp0 + k0);
    gload16(blds1, bgp1 + k0);
    __syncthreads();

    bf16x8 af[4], bfr[4];
    #pragma unroll
    for (int i = 0; i < 4; ++i) af[i]  = *(const bf16x8*)&As[wm + i * 16 + lr][lk];
    #pragma unroll
    for (int j = 0; j < 4; ++j) bfr[j] = *(const bf16x8*)&Bs[wn + j * 16 + lr][lk];
    #pragma unroll
    for (int i = 0; i < 4; ++i)
      #pragma unroll
      for (int j = 0; j < 4; ++j)
        acc[i][j] = __builtin_amdgcn_mfma_f32_16x16x32_bf16(af[i], bfr[j], acc[i][j], 0, 0, 0);
  }

  const int q4 = (lane >> 4) << 2;
  const int colb = n0 + wn;
  #pragma unroll
  for (int i = 0; i < 4; ++i) {
    #pragma unroll
    for (int r = 0; r < 4; ++r) {
      const int mm = m0 + wm + i * 16 + q4 + r;
      if (EPI == 0) {
        const int pp = mm % NPATCH;
        const float* pe = pos + (size_t)pp * DMODEL;
        bf16_t* orow = (bf16_t*)outp + (size_t)mm * DMODEL;
        #pragma unroll
        for (int j = 0; j < 4; ++j) {
          const int nn = colb + j * 16 + lr;
          orow[nn] = (bf16_t)(acc[i][j][r] + bias[nn] + pe[nn]);
        }
      } else {
        float* orow = (float*)outp + (size_t)mm * DMODEL;
        #pragma unroll
        for (int j = 0; j < 4; ++j) {
          const int nn = colb + j * 16 + lr;
          orow[nn] = acc[i][j][r] + bias[nn];
        }
      }
    }
  }
}

// ---------------------------------------------------------------------------
// fallback gemm1 (fused patchify) — used only if ws too small
// ---------------------------------------------------------------------------
__global__ __launch_bounds__(256) void gemm1_fused_fallback(
    const float* __restrict__ images, const bf16_t* __restrict__ WpT,
    const float* __restrict__ b_patch, const float* __restrict__ pos_embed,
    bf16_t* __restrict__ xout)
{
  __shared__ bf16_t As[128][40];
  __shared__ bf16_t Bs[128][40];
  const int tid = threadIdx.x;
  const int n0 = blockIdx.x * 128;
  const int m0 = blockIdx.y * 128;
  const int sr = tid >> 1;
  const int sh = tid & 1;
  const int m  = m0 + sr;
  const int b  = m / NPATCH;
  const int p  = m - b * NPATCH;
  const int ph = p / NHP;
  const int pw = p - ph * NHP;
  const float* abase = images + (size_t)(b * 3) * (IMG * IMG)
                              + (size_t)(ph * PSZ) * IMG + pw * PSZ;
  const bf16_t* brow = WpT + (size_t)(n0 + sr) * PDIM + sh * 16;
  const int wave = tid >> 6;
  const int lane = tid & 63;
  const int wm = (wave >> 1) << 6;
  const int wn = (wave & 1) << 6;
  const int lr = lane & 15;
  const int lk = (lane >> 4) << 3;
  f32x4 acc[4][4] = {};
  for (int ks = 0; ks < PDIM / 32; ++ks) {
    const int k0 = ks * 32;
    const int c  = k0 >> 8;
    const int ib = (k0 >> 4) & 15;
    const float* asrc = abase + (size_t)c * (IMG * IMG) + (ib + sh) * IMG;
    const float4 av0 = *(const float4*)(asrc + 0);
    const float4 av1 = *(const float4*)(asrc + 4);
    const float4 av2 = *(const float4*)(asrc + 8);
    const float4 av3 = *(const float4*)(asrc + 12);
    const uint4 bv0 = *(const uint4*)(brow + k0);
    const uint4 bv1 = *(const uint4*)(brow + k0 + 8);
    __syncthreads();
    bf16x8 a0, a1;
    a0[0] = (bf16_t)av0.x; a0[1] = (bf16_t)av0.y; a0[2] = (bf16_t)av0.z; a0[3] = (bf16_t)av0.w;
    a0[4] = (bf16_t)av1.x; a0[5] = (bf16_t)av1.y; a0[6] = (bf16_t)av1.z; a0[7] = (bf16_t)av1.w;
    a1[0] = (bf16_t)av2.x; a1[1] = (bf16_t)av2.y; a1[2] = (bf16_t)av2.z; a1[3] = (bf16_t)av2.w;
    a1[4] = (bf16_t)av3.x; a1[5] = (bf16_t)av3.y; a1[6] = (bf16_t)av3.z; a1[7] = (bf16_t)av3.w;
    *(bf16x8*)&As[sr][sh * 16]     = a0;
    *(bf16x8*)&As[sr][sh * 16 + 8] = a1;
    *(uint4*)&Bs[sr][sh * 16]      = bv0;
    *(uint4*)&Bs[sr][sh * 16 + 8]  = bv1;
    __syncthreads();
    bf16x8 af[4], bfr[4];
    #pragma unroll
    for (int i = 0; i < 4; ++i) af[i]  = *(const bf16x8*)&As[wm + i * 16 + lr][lk];
    #pragma unroll
    for (int j = 0; j < 4; ++j) bfr[j] = *(const bf16x8*)&Bs[wn + j * 16 + lr][lk];
    #pragma unroll
    for (int i = 0; i < 4; ++i)
      #pragma unroll
      for (int j = 0; j < 4; ++j)
        acc[i][j] = __builtin_amdgcn_mfma_f32_16x16x32_bf16(af[i], bfr[j], acc[i][j], 0, 0, 0);
  }
  const int colb = n0 + wn;
  #pragma unroll
  for (int i = 0; i < 4; ++i) {
    #pragma unroll
    for (int r = 0; r < 4; ++r) {
      const int mm = m0 + wm + i * 16 + ((lane >> 4) << 2) + r;
      const int pp = mm % NPATCH;
      const float* pe = pos_embed + (size_t)pp * DMODEL;
      bf16_t* orow = xout + (size_t)mm * DMODEL;
      #pragma unroll
      for (int j = 0; j < 4; ++j) {
        const int nn = colb + j * 16 + lr;
        orow[nn] = (bf16_t)(acc[i][j][r] + b_patch[nn] + pe[nn]);
      }
    }
  }
}

// ---------------------------------------------------------------------------
// manifold_ln_v3: MFMA-based manifold + LayerNorm, in-place on x (bf16)
// grid 392 blocks x 256 threads; each wave owns 16 rows.
// Phase 1: C1[16][16] = x_tile @ Wcs^T  (coords 0-7, spinor hi 8-11, lo 12-15)
//          + Wcs2 correction for coord lo bits.
// K0 via hi/lo pairing (shfl_xor 4) + 16-lane reduce.
// Phase 2: coords -> cT LDS transpose -> A2 frag (hi k0-7 | lo k8-15 | 1,1 k16-17)
// Phase 3: per 16-col frag j: acc2 = mfma(A2, WeT-frag) (= coords@We + be);
//          xe = acc2*K0 + x (residual re-read); stats; pack bf16.
// LN: 16-lane reduce of s1/s2; unpack, scale by gamma/beta, store.
// ---------------------------------------------------------------------------
__global__ __launch_bounds__(256) void manifold_ln_v3(
    bf16_t* __restrict__ x,
    const bf16_t* __restrict__ Wcsg, const bf16_t* __restrict__ Wcs2g,
    const bf16_t* __restrict__ Wetg,
    const float* __restrict__ b_coord, const float* __restrict__ b_spinor,
    const float* __restrict__ ln_gamma, const float* __restrict__ ln_beta)
{
  __shared__ bf16_t sWcs[16 * 512];   // XOR-swizzled: byte ^= (row&7)<<4
  __shared__ bf16_t sWcs2[8 * 512];   // XOR-swizzled
  __shared__ bf16_t sWeT[512 * 24];   // linear, row stride 48B
  __shared__ float  cT[4][16][12];
  __shared__ bf16_t sg[512], sb[512];

  const int tid = threadIdx.x;

  // ---- stage weights into LDS ----
  #pragma unroll
  for (int i = 0; i < 4; ++i) {
    const int c = tid + 256 * i;                 // 1024 x 16B chunks
    const int r = c >> 6, off = (c & 63) * 16;
    const uint4 v = *(const uint4*)((const char*)Wcsg + (size_t)c * 16);
    *(uint4*)((char*)sWcs + ((r * 1024 + off) ^ ((r & 7) << 4))) = v;
  }
  #pragma unroll
  for (int i = 0; i < 2; ++i) {
    const int c = tid + 256 * i;                 // 512 x 16B chunks
    const int r = c >> 6, off = (c & 63) * 16;
    const uint4 v = *(const uint4*)((const char*)Wcs2g + (size_t)c * 16);
    *(uint4*)((char*)sWcs2 + ((r * 1024 + off) ^ ((r & 7) << 4))) = v;
  }
  #pragma unroll
  for (int i = 0; i < 6; ++i) {
    const int c = tid + 256 * i;                 // 1536 x 16B chunks
    *(uint4*)((char*)sWeT + (size_t)c * 16) =
        *(const uint4*)((const char*)Wetg + (size_t)c * 16);
  }
  for (int i = tid; i < 512; i += 256) {
    sg[i] = (bf16_t)ln_gamma[i];
    sb[i] = (bf16_t)ln_beta[i];
  }
  __syncthreads();

  const int w    = tid >> 6;
  const int lane = tid & 63;
  const int lr   = lane & 15;
  const int lk   = (lane >> 4) << 3;    // 0,8,16,24
  const int q4   = (lane >> 4) << 2;    // 0,4,8,12
  const int m0w  = blockIdx.x * 64 + w * 16;

  const float bcs = (lr < 8) ? b_coord[lr] : (lr < 12 ? b_spinor[lr - 8] : 0.f);

  // ---- phase 1: C1 = x_tile @ Wcs^T ----
  const bf16_t* xrow = x + (size_t)(m0w + lr) * DMODEL + lk;
  f32x4 acc1  = {0.f, 0.f, 0.f, 0.f};
  f32x4 acc1b = {0.f, 0.f, 0.f, 0.f};
  const bf16_t zb = (bf16_t)0.f;
  #pragma unroll
  for (int ks = 0; ks < 16; ++ks) {
    const bf16x8 af = *(const bf16x8*)(xrow + ks * 32);
    const int wb = (lr * 1024 + ks * 64 + lk * 2) ^ ((lr & 7) << 4);
    const bf16x8 w1 = *(const bf16x8*)((const char*)sWcs + wb);
    acc1 = __builtin_amdgcn_mfma_f32_16x16x32_bf16(af, w1, acc1, 0, 0, 0);
    bf16x8 w2 = {zb, zb, zb, zb, zb, zb, zb, zb};
    if (lr < 8) w2 = *(const bf16x8*)((const char*)sWcs2 + wb);
    acc1b = __builtin_amdgcn_mfma_f32_16x16x32_bf16(af, w2, acc1b, 0, 0, 0);
  }

  // ---- K0 + coords to cT ----
  float k0r[4], svals[4];
  #pragma unroll
  for (int r = 0; r < 4; ++r) {
    const float s = acc1[r] + acc1b[r] + bcs;
    svals[r] = s;
    if (lr < 8) cT[w][q4 + r][lr] = s;
  }
  #pragma unroll
  for (int r = 0; r < 4; ++r) {
    const float sp = svals[r] + __shfl_xor(svals[r], 4, 64);
    float sq = (lr >= 8 && lr < 12) ? sp * sp : 0.f;
    sq += __shfl_xor(sq, 1, 64);
    sq += __shfl_xor(sq, 2, 64);
    sq += __shfl_xor(sq, 4, 64);
    sq += __shfl_xor(sq, 8, 64);
    k0r[r] = sq;
  }
  __syncthreads();   // cT visible (block-wide barrier, uniform)

  // ---- build A2 frag ----
  const f32x4 c0 = *(const f32x4*)&cT[w][lr][0];
  const f32x4 c4 = *(const f32x4*)&cT[w][lr][4];
  const bf16_t oneb = (bf16_t)1.0f;
  bf16x8 a2;
  #pragma unroll
  for (int j = 0; j < 8; ++j) {
    const float cv = (j < 4) ? c0[j] : c4[j - 4];
    const bf16_t hi = (bf16_t)cv;
    const bf16_t lo = (bf16_t)(cv - (float)hi);
    bf16_t v;
    if (lk == 0)       v = hi;
    else if (lk == 8)  v = lo;
    else if (lk == 16) v = (j < 2) ? oneb : zb;
    else               v = zb;
    a2[j] = v;
  }

  // ---- phase 3: embed + residual + stats ----
  const bf16_t* xres = x + (size_t)(m0w + q4) * DMODEL + lr;
  unsigned xp[4][16];
  float s1[4] = {0.f, 0.f, 0.f, 0.f};
  float s2[4] = {0.f, 0.f, 0.f, 0.f};
  const int woff = (lk & 16) ? 32 : lk * 2;
  #pragma unroll
  for (int j = 0; j < 32; ++j) {
    const int n = j * 16 + lr;
    bf16x8 wf = *(const bf16x8*)((const char*)sWeT + n * 48 + woff);
    if (lk == 24) {
      #pragma unroll
      for (int t = 0; t < 8; ++t) wf[t] = zb;
    }
    f32x4 acc2 = {0.f, 0.f, 0.f, 0.f};
    acc2 = __builtin_amdgcn_mfma_f32_16x16x32_bf16(a2, wf, acc2, 0, 0, 0);
    #pragma unroll
    for (int r = 0; r < 4; ++r) {
      const float xg = (float)xres[(size_t)r * DMODEL + j * 16];
      const float xe = acc2[r] * k0r[r] + xg;
      s1[r] += xe;
      s2[r] += xe * xe;
      const unsigned short ub = bfbits(xe);
      if ((j & 1) == 0) xp[r][j >> 1] = ub;
      else              xp[r][j >> 1] |= ((unsigned)ub) << 16;
    }
  }

  // ---- LN stats (16-lane reduce) ----
  float mu[4], rsg[4];
  #pragma unroll
  for (int r = 0; r < 4; ++r) {
    float a = s1[r], b2 = s2[r];
    #pragma unroll
    for (int off = 1; off <= 8; off <<= 1) {
      a  += __shfl_xor(a, off, 64);
      b2 += __shfl_xor(b2, off, 64);
    }
    const float m = a * (1.f / 512.f);
    const float v = b2 * (1.f / 512.f) - m * m;
    mu[r]  = m;
    rsg[r] = rsqrtf(v + 1e-5f);
  }

  // ---- normalize + store ----
  bf16_t* xo = x + (size_t)(m0w + q4) * DMODEL;
  #pragma unroll
  for (int jp = 0; jp < 16; ++jp) {
    const int n0 = jp * 32 + lr, n1 = n0 + 16;
    const float g0 = (float)sg[n0], bb0 = (float)sb[n0];
    const float g1 = (float)sg[n1], bb1 = (float)sb[n1];
    #pragma unroll
    for (int r = 0; r < 4; ++r) {
      const unsigned p = xp[r][jp];
      const float flo = f_from_bits(p << 16);
      const float fhi = f_from_bits(p & 0xffff0000u);
      const float o0 = (flo - mu[r]) * rsg[r] * g0 + bb0;
      const float o1 = (fhi - mu[r]) * rsg[r] * g1 + bb1;
      xo[(size_t)r * DMODEL + n0] = (bf16_t)o0;
      xo[(size_t)r * DMODEL + n1] = (bf16_t)o1;
    }
  }
}

// ---------------------------------------------------------------------------
extern "C" void kernel_launch(void* const* d_in, const int* in_sizes, int n_in,
                              void* d_out, int out_size, void* d_ws, size_t ws_size,
                              hipStream_t stream)
{
  const float* images    = (const float*)d_in[0];
  const float* W_patch   = (const float*)d_in[1];
  const float* b_patch   = (const float*)d_in[2];
  const float* pos_embed = (const float*)d_in[3];
  const float* W_coord   = (const float*)d_in[4];
  const float* b_coord   = (const float*)d_in[5];
  const float* W_spinor  = (const float*)d_in[6];
  const float* b_spinor  = (const float*)d_in[7];
  const float* W_embed   = (const float*)d_in[8];
  const float* b_embed   = (const float*)d_in[9];
  const float* ln_gamma  = (const float*)d_in[10];
  const float* ln_beta   = (const float*)d_in[11];
  const float* W_out     = (const float*)d_in[12];
  const float* b_out     = (const float*)d_in[13];
  float* out = (float*)d_out;

  const size_t SZ_APAT = (size_t)MROWS * PDIM * 2;     // 38,535,168
  const size_t SZ_X    = (size_t)MROWS * DMODEL * 2;   // 25,690,112
  const size_t SZ_WPT  = (size_t)DMODEL * PDIM * 2;    //    786,432
  const size_t SZ_WOT  = (size_t)DMODEL * DMODEL * 2;  //    524,288
  const size_t SZ_WCS  = 16 * 512 * 2;                 //     16,384
  const size_t SZ_WCS2 = 8 * 512 * 2;                  //      8,192
  const size_t SZ_WET  = 512 * 24 * 2;                 //     24,576
  const size_t NEED_FULL = SZ_APAT + SZ_X + SZ_WPT + SZ_WOT + SZ_WCS + SZ_WCS2 + SZ_WET;

  char* ws = (char*)d_ws;
  const bool full = (ws_size >= NEED_FULL);

  bf16_t *Apat, *x, *WpT, *WoT, *Wcsg, *Wcs2g, *Wetg;
  if (full) {
    char* p = ws;
    Apat  = (bf16_t*)p;            p += SZ_APAT;
    x     = (bf16_t*)p;            p += SZ_X;
    WpT   = (bf16_t*)p;            p += SZ_WPT;
    WoT   = (bf16_t*)p;            p += SZ_WOT;
    Wcsg  = (bf16_t*)p;            p += SZ_WCS;
    Wcs2g = (bf16_t*)p;            p += SZ_WCS2;
    Wetg  = (bf16_t*)p;
  } else {
    char* p = ws;
    Apat  = nullptr;
    x     = (bf16_t*)p;            p += SZ_X;
    WpT   = (bf16_t*)p;            p += SZ_WPT;
    WoT   = (bf16_t*)p;            p += SZ_WOT;
    Wcsg  = (bf16_t*)p;            p += SZ_WCS;
    Wcs2g = (bf16_t*)p;            p += SZ_WCS2;
    Wetg  = (bf16_t*)p;
  }

  hipLaunchKernelGGL(transpose_to_bf16, dim3(8, 12), dim3(64, 4), 0, stream,
                     W_patch, WpT, PDIM, DMODEL);
  hipLaunchKernelGGL(transpose_to_bf16, dim3(8, 8), dim3(64, 4), 0, stream,
                     W_out, WoT, DMODEL, DMODEL);
  hipLaunchKernelGGL(manifold_prep, dim3(96), dim3(256), 0, stream,
                     W_coord, W_spinor, W_embed, b_embed, Wcsg, Wcs2g, Wetg);

  if (full) {
    hipLaunchKernelGGL(patchify_bf16, dim3(32 * 3 * 28), dim3(256), 0, stream,
                       images, Apat);
    hipLaunchKernelGGL((gemm_bf16<PDIM, 0>), dim3(784), dim3(256), 0, stream,
                       Apat, WpT, b_patch, pos_embed, (void*)x);
  } else {
    hipLaunchKernelGGL(gemm1_fused_fallback, dim3(4, 196), dim3(256), 0, stream,
                       images, WpT, b_patch, pos_embed, x);
  }

  hipLaunchKernelGGL(manifold_ln_v3, dim3(392), dim3(256), 0, stream,
                     x, Wcsg, Wcs2g, Wetg, b_coord, b_spinor, ln_gamma, ln_beta);

  hipLaunchKernelGGL((gemm_bf16<DMODEL, 1>), dim3(784), dim3(256), 0, stream,
                     x, WoT, b_out, (const float*)nullptr, (void*)out);
}